// Round 7
// baseline (121.977 us; speedup 1.0000x reference)
//
#include <hip/hip_runtime.h>
#include <stdint.h>

#define C 64
#define HH 112
#define WWD 112
#define HW 12544
#define NB 32
#define MTOT (NB*HW)
#define PLANE_SH 25088      // shorts per plane stride (plane = 50176 bytes)
#define PLANE_BYTES 50176
#define ROWB 7168           // bytes per sign row (112*64)
#define HOLE_OFF 25088      // byte offset of sign-hole within a plane

typedef int v4i  __attribute__((ext_vector_type(4)));
typedef int v16i __attribute__((ext_vector_type(16)));

// sign8 row R (R = n*112 + h) lives in the upper half of plane (R/3), 3 rows/hole
__device__ __forceinline__ const char* sign_row_c(const char* outb, int R) {
    return outb + (size_t)(R/3)*PLANE_BYTES + HOLE_OFF + (size_t)(R%3)*ROWB;
}
__device__ __forceinline__ char* sign_row(char* outb, int R) {
    return outb + (size_t)(R/3)*PLANE_BYTES + HOLE_OFF + (size_t)(R%3)*ROWB;
}

// ---- K1: pack sign(x+b0) as NHWC int8 into d_out holes (blocks 0..1567)
//          + weight int8 prep [o][tap][c] + wscale (block 1568)
__global__ __launch_bounds__(256) void k_pack(
        const float* __restrict__ x, const float* __restrict__ b0,
        const float* __restrict__ w,
        char* __restrict__ outb, char* __restrict__ A8, float* __restrict__ wscale) {
    int bid = blockIdx.x;
    if (bid < 1568) {
        int p = bid*256 + threadIdx.x;      // global pixel 0..401407
        int n = p / HW, hw = p - n*HW;
        int h = hw / WWD, wc = hw - h*WWD;
        const float* xb = x + (size_t)n*C*HW + hw;
        uint32_t packs[16];
        #pragma unroll
        for (int cq = 0; cq < 16; ++cq) {
            uint32_t u = 0;
            #pragma unroll
            for (int j = 0; j < 4; ++j) {
                int c = cq*4 + j;
                float v = xb[(size_t)c*HW] + b0[c];
                char sg = v > 0.f ? 1 : (v < 0.f ? -1 : 0);
                u |= ((uint32_t)(uint8_t)sg) << (8*j);
            }
            packs[cq] = u;
        }
        uint4* d4 = (uint4*)(sign_row(outb, n*HH + h) + wc*64);
        #pragma unroll
        for (int j = 0; j < 4; ++j)
            d4[j] = make_uint4(packs[j*4], packs[j*4+1], packs[j*4+2], packs[j*4+3]);
    } else {
        int t = threadIdx.x;
        int o = t >> 2, part = t & 3;
        float s = 0.f;
        for (int cc = 0; cc < 16; ++cc) {
            int c = part*16 + cc;
            const float* wp = w + ((size_t)o*C + c)*9;
            #pragma unroll
            for (int tap = 0; tap < 9; ++tap) {
                float v = wp[tap];
                s += fabsf(v);
                A8[(o*9 + tap)*64 + c] = v > 0.f ? (char)1 : (char)-1;
            }
        }
        __shared__ float pabs[256];
        pabs[t] = s;
        __syncthreads();
        if (t < 64)
            wscale[t] = (pabs[t*4]+pabs[t*4+1]+pabs[t*4+2]+pabs[t*4+3]) * (1.0f/576.0f);
    }
}

// ---- K2: i8-MFMA conv. Block = (row-pair, image); LDS stages 4 rows x 114 cols
//          x 64 ch (80B col stride for bank spread). Wave = o-half, loops px-tiles.
__global__ __launch_bounds__(256) void k_conv(
        const char* __restrict__ signb, const char* __restrict__ A8,
        short* __restrict__ cv16) {
    __shared__ __align__(16) char lds8[4*114*80];
    int n  = blockIdx.y;
    int rb = blockIdx.x * 2;          // rows rb, rb+1

    // stage rows rb-1..rb+2 (zero OOB rows)
    for (int it = threadIdx.x; it < 4*448; it += 256) {
        int ri = it / 448;
        int k  = it - ri*448;         // uint4 index in row
        int col = k >> 2;
        int b   = (k & 3) * 16;
        int Rr = rb - 1 + ri;
        uint4 v = make_uint4(0,0,0,0);
        if (Rr >= 0 && Rr < HH)
            v = ((const uint4*)sign_row_c(signb, n*HH + Rr))[k];
        *(uint4*)&lds8[(ri*114 + col + 1)*80 + b] = v;
    }
    // zero halo cols 0 and 113
    if (threadIdx.x < 32) {
        int r   = threadIdx.x >> 3;
        int col = ((threadIdx.x >> 2) & 1) * 113;
        int j   = threadIdx.x & 3;
        *(uint4*)&lds8[(r*114 + col)*80 + j*16] = make_uint4(0,0,0,0);
    }

    int lane  = threadIdx.x & 63;
    int wv    = threadIdx.x >> 6;
    int ot    = wv & 1;               // o-half
    int gsel  = lane >> 5;            // k-group
    int olane = ot*32 + (lane & 31);

    v4i afr[9][2];
    #pragma unroll
    for (int tap = 0; tap < 9; ++tap) {
        #pragma unroll
        for (int h = 0; h < 2; ++h)
            afr[tap][h] = *(const v4i*)(A8 + (size_t)(olane*9 + tap)*64 + h*32 + gsel*16);
    }
    __syncthreads();

    for (int T = (wv >> 1); T < 7; T += 2) {
        int px   = T*32 + (lane & 31);          // 0..223 within row-pair
        int roff = px >= WWD ? 1 : 0;
        int cpx  = px - roff*WWD;
        v16i accA = {0,0,0,0,0,0,0,0,0,0,0,0,0,0,0,0};
        v16i accB = {0,0,0,0,0,0,0,0,0,0,0,0,0,0,0,0};
        #pragma unroll
        for (int kh = 0; kh < 3; ++kh) {
            #pragma unroll
            for (int kw = 0; kw < 3; ++kw) {
                const char* bp = &lds8[((roff+kh)*114 + (cpx+kw))*80 + gsel*16];
                v4i b0v = *(const v4i*)bp;
                v4i b1v = *(const v4i*)(bp + 32);
                accA = __builtin_amdgcn_mfma_i32_32x32x32_i8(afr[kh*3+kw][0], b0v, accA, 0, 0, 0);
                accB = __builtin_amdgcn_mfma_i32_32x32x32_i8(afr[kh*3+kw][1], b1v, accB, 0, 0, 0);
            }
        }
        v16i acc = accA + accB;
        size_t pixbase = (size_t)rb*WWD + px;
        #pragma unroll
        for (int r = 0; r < 16; ++r) {
            int o = ot*32 + (r & 3) + 8*(r >> 2) + 4*gsel;
            cv16[(size_t)(n*C + o)*PLANE_SH + pixbase] = (short)acc[r];
        }
    }
}

// ---- K2b: per-plane exact integer stats (no atomics, no zeroing)
__global__ __launch_bounds__(256) void k_stats(
        const short* __restrict__ cv16, int* __restrict__ ps,
        long long* __restrict__ pq) {
    int plane = blockIdx.x;
    const uint2* p = (const uint2*)(cv16 + (size_t)plane*PLANE_SH);
    int s = 0; unsigned q = 0;
    for (int i = threadIdx.x; i < 3136; i += 256) {
        uint2 u = p[i];
        int v0 = (int)(short)(u.x & 0xFFFF), v1 = (int)(short)(u.x >> 16);
        int v2 = (int)(short)(u.y & 0xFFFF), v3 = (int)(short)(u.y >> 16);
        s += (v0+v1) + (v2+v3);
        q += (unsigned)(v0*v0 + v1*v1) + (unsigned)(v2*v2 + v3*v3);
    }
    __shared__ int ls[256];
    __shared__ unsigned long long lq[256];
    ls[threadIdx.x] = s; lq[threadIdx.x] = q;
    __syncthreads();
    for (int st = 128; st > 0; st >>= 1) {
        if ((int)threadIdx.x < st) {
            ls[threadIdx.x] += ls[threadIdx.x+st];
            lq[threadIdx.x] += lq[threadIdx.x+st];
        }
        __syncthreads();
    }
    if (threadIdx.x == 0) { ps[plane] = ls[0]; pq[plane] = (long long)lq[0]; }
}

// ---- K3: streaming finish (register-staged in-place), one block per plane
__global__ __launch_bounds__(256) void k_finish(
        const short* __restrict__ cv16, const float* __restrict__ x,
        const int* __restrict__ ps, const long long* __restrict__ pq,
        const float* __restrict__ wscale, const float* __restrict__ gamma,
        const float* __restrict__ beta, const float* __restrict__ b1,
        const float* __restrict__ alpha, const float* __restrict__ b2,
        float* __restrict__ out) {
    int o = blockIdx.x, n = blockIdx.y;
    size_t plane = (size_t)n*C + o;

    int s = 0; long long q = 0;
    #pragma unroll 8
    for (int nn = 0; nn < NB; ++nn) { s += ps[nn*C + o]; q += pq[nn*C + o]; }
    const float inv = 1.0f / (float)MTOT;
    float sc   = wscale[o];
    float mean = (float)s * inv;
    float ek2  = (float)q * inv;
    float mu   = sc * mean;
    float var  = sc*sc*ek2 - mu*mu;
    float g    = gamma[o] * rsqrtf(var + 1e-5f);
    float A    = g * sc;
    float B    = beta[o] - g*mu + b1[o];
    float al   = alpha[o];
    float bb2  = b2[o];

    const uint2* cv2 = (const uint2*)(cv16 + plane*PLANE_SH);
    uint2 rbuf[13];
    #pragma unroll
    for (int k = 0; k < 13; ++k) {
        int i = threadIdx.x + k*256;
        if (i < 3136) rbuf[k] = cv2[i];
    }
    __syncthreads();

    const float4* x4 = (const float4*)x + plane*3136;
    float4*       o4 = (float4*)out     + plane*3136;
    #pragma unroll
    for (int k = 0; k < 13; ++k) {
        int i = threadIdx.x + k*256;
        if (i < 3136) {
            uint2 u = rbuf[k];
            float4 xv = x4[i], r;
            float t;
            t = A * (float)(int)(short)(u.x & 0xFFFF) + B + xv.x; t = t > 0.f ? t : al*t; r.x = t + bb2;
            t = A * (float)(int)(short)(u.x >> 16)    + B + xv.y; t = t > 0.f ? t : al*t; r.y = t + bb2;
            t = A * (float)(int)(short)(u.y & 0xFFFF) + B + xv.z; t = t > 0.f ? t : al*t; r.z = t + bb2;
            t = A * (float)(int)(short)(u.y >> 16)    + B + xv.w; t = t > 0.f ? t : al*t; r.w = t + bb2;
            o4[i] = r;
        }
    }
}

extern "C" void kernel_launch(void* const* d_in, const int* in_sizes, int n_in,
                              void* d_out, int out_size, void* d_ws, size_t ws_size,
                              hipStream_t stream) {
    const float* x     = (const float*)d_in[0];
    const float* b0    = (const float*)d_in[1];
    const float* w     = (const float*)d_in[2];
    const float* gamma = (const float*)d_in[3];
    const float* beta  = (const float*)d_in[4];
    const float* b1    = (const float*)d_in[5];
    const float* alpha = (const float*)d_in[6];
    const float* b2    = (const float*)d_in[7];

    char* ws = (char*)d_ws;
    char*      A8     = ws;                                   // 36,864 B
    float*     wscale = (float*)(ws + 36864);                 // 256 B
    int*       ps     = (int*)(ws + 37120);                   // 8,192 B
    long long* pq     = (long long*)(ws + 45312);             // 16,384 B

    char*  outb = (char*)d_out;
    short* cv16 = (short*)d_out;

    hipLaunchKernelGGL(k_pack, dim3(1569), dim3(256), 0, stream,
                       x, b0, w, outb, A8, wscale);
    hipLaunchKernelGGL(k_conv, dim3(56, 32), dim3(256), 0, stream,
                       outb, A8, cv16);
    hipLaunchKernelGGL(k_stats, dim3(2048), dim3(256), 0, stream,
                       cv16, ps, pq);
    hipLaunchKernelGGL(k_finish, dim3(64, 32), dim3(256), 0, stream,
                       cv16, x, ps, pq, wscale, gamma, beta, b1, alpha, b2,
                       (float*)d_out);
}

// Round 8
// 120.549 us; speedup vs baseline: 1.0119x; 1.0119x over previous
//
#include <hip/hip_runtime.h>
#include <stdint.h>

#define C 64
#define HH 112
#define WWD 112
#define HW 12544
#define NB 32
#define MTOT (NB*HW)
#define PLANE_SH 25088      // shorts per plane stride (plane = 50176 bytes)
#define PLANE_BYTES 50176
#define ROWB 7168           // bytes per sign row (112*64)
#define HOLE_OFF 25088      // byte offset of sign-hole within a plane

typedef int v4i  __attribute__((ext_vector_type(4)));
typedef int v16i __attribute__((ext_vector_type(16)));
typedef unsigned long long ull;

// sign8 row R (R = n*112 + h) lives in the upper half of plane (R/3), 3 rows/hole
__device__ __forceinline__ const char* sign_row_c(const char* outb, int R) {
    return outb + (size_t)(R/3)*PLANE_BYTES + HOLE_OFF + (size_t)(R%3)*ROWB;
}
__device__ __forceinline__ char* sign_row(char* outb, int R) {
    return outb + (size_t)(R/3)*PLANE_BYTES + HOLE_OFF + (size_t)(R%3)*ROWB;
}

// ---- K1: pack sign(x+b0) as NHWC int8 into d_out holes (blocks 0..1567)
//          via LDS transpose for coalesced 1KB stores; weight prep (block 1568)
__global__ __launch_bounds__(256) void k_pack(
        const float* __restrict__ x, const float* __restrict__ b0,
        const float* __restrict__ w,
        char* __restrict__ outb, char* __restrict__ A8, float* __restrict__ wscale) {
    int bid = blockIdx.x;
    if (bid < 1568) {
        __shared__ ull Tl[256*9];           // 72B rows: 2-way banks (free)
        int tid = threadIdx.x;
        int n    = bid / 49;
        int pimg = (bid % 49) * 256 + tid;  // pixel within image (block ⊂ one image)
        const float* xb = x + (size_t)n*C*HW + pimg;
        ull row[8];
        #pragma unroll
        for (int k = 0; k < 8; ++k) {
            ull r = 0;
            #pragma unroll
            for (int j = 0; j < 8; ++j) {
                int c = k*8 + j;
                float v = xb[(size_t)c*HW] + b0[c];
                int sg = v > 0.f ? 1 : (v < 0.f ? 0xFF : 0);
                r |= ((ull)(unsigned)sg) << (8*j);
            }
            row[k] = r;
        }
        #pragma unroll
        for (int k = 0; k < 8; ++k) Tl[tid*9 + k] = row[k];
        __syncthreads();
        int wv = tid >> 6, L = tid & 63;
        #pragma unroll
        for (int j = 0; j < 4; ++j) {
            int prow = wv*64 + j*16 + (L >> 2);   // pixel row in LDS
            int cch  = L & 3;                     // 16B chunk
            ull a0 = Tl[prow*9 + cch*2];
            ull a1 = Tl[prow*9 + cch*2 + 1];
            int pb = (bid % 49)*256 + wv*64 + j*16;   // 16-aligned → single row
            int hg = pb / WWD;
            int wg = pb - hg*WWD;
            char* dst = sign_row(outb, n*HH + hg) + wg*64 + (size_t)L*16;
            uint4 val;
            val.x = (uint32_t)a0; val.y = (uint32_t)(a0 >> 32);
            val.z = (uint32_t)a1; val.w = (uint32_t)(a1 >> 32);
            *(uint4*)dst = val;   // lane-contiguous: 1KB coalesced per wave
        }
    } else {
        int t = threadIdx.x;
        int o = t >> 2, part = t & 3;
        float s = 0.f;
        for (int cc = 0; cc < 16; ++cc) {
            int c = part*16 + cc;
            const float* wp = w + ((size_t)o*C + c)*9;
            #pragma unroll
            for (int tap = 0; tap < 9; ++tap) {
                float v = wp[tap];
                s += fabsf(v);
                A8[(o*9 + tap)*64 + c] = v > 0.f ? (char)1 : (char)-1;
            }
        }
        __shared__ float pabs[256];
        pabs[t] = s;
        __syncthreads();
        if (t < 64)
            wscale[t] = (pabs[t*4]+pabs[t*4+1]+pabs[t*4+2]+pabs[t*4+3]) * (1.0f/576.0f);
    }
}

// ---- K2: i8-MFMA conv. LDS col stride 72B (2-way banks, free), b64 reads.
__global__ __launch_bounds__(256) void k_conv(
        const char* __restrict__ signb, const char* __restrict__ A8,
        short* __restrict__ cv16) {
    __shared__ ull ldsq[4*114*9];       // 32832 B
    int n  = blockIdx.y;
    int rb = blockIdx.x * 2;            // rows rb, rb+1

    // stage rows rb-1..rb+2 (zero OOB rows)
    for (int it = threadIdx.x; it < 4*448; it += 256) {
        int ri = it / 448;
        int k  = it - ri*448;           // uint4 index in row
        int col = k >> 2;
        int b   = k & 3;
        int Rr = rb - 1 + ri;
        uint4 v = make_uint4(0,0,0,0);
        if (Rr >= 0 && Rr < HH)
            v = ((const uint4*)sign_row_c(signb, n*HH + Rr))[k];
        ull* d = &ldsq[((size_t)(ri*114 + col + 1))*9 + b*2];
        d[0] = ((ull)v.y << 32) | v.x;
        d[1] = ((ull)v.w << 32) | v.z;
    }
    // zero halo cols 0 and 113 (4 rows x 2 cols x 9 ulongs = 72)
    if (threadIdx.x < 72) {
        int r = threadIdx.x / 18, rest = threadIdx.x % 18;
        int col = (rest / 9) * 113, q = rest % 9;
        ldsq[((size_t)(r*114 + col))*9 + q] = 0ull;
    }

    int lane  = threadIdx.x & 63;
    int wv    = threadIdx.x >> 6;
    int ot    = wv & 1;                 // o-half
    int gsel  = lane >> 5;              // k-group
    int olane = ot*32 + (lane & 31);

    v4i afr[9][2];
    #pragma unroll
    for (int tap = 0; tap < 9; ++tap) {
        #pragma unroll
        for (int h = 0; h < 2; ++h)
            afr[tap][h] = *(const v4i*)(A8 + (size_t)(olane*9 + tap)*64 + h*32 + gsel*16);
    }
    __syncthreads();

    for (int T = (wv >> 1); T < 7; T += 2) {
        int px   = T*32 + (lane & 31);          // 0..223 within row-pair
        int roff = px >= WWD ? 1 : 0;
        int cpx  = px - roff*WWD;
        v16i accA = {0,0,0,0,0,0,0,0,0,0,0,0,0,0,0,0};
        v16i accB = {0,0,0,0,0,0,0,0,0,0,0,0,0,0,0,0};
        #pragma unroll
        for (int kh = 0; kh < 3; ++kh) {
            #pragma unroll
            for (int kw = 0; kw < 3; ++kw) {
                const ull* bp = &ldsq[((size_t)((roff+kh)*114 + (cpx+kw)))*9];
                ull lo0 = bp[gsel*2],     hi0 = bp[gsel*2 + 1];
                ull lo1 = bp[gsel*2 + 4], hi1 = bp[gsel*2 + 5];
                v4i b0v = {(int)lo0, (int)(lo0>>32), (int)hi0, (int)(hi0>>32)};
                v4i b1v = {(int)lo1, (int)(lo1>>32), (int)hi1, (int)(hi1>>32)};
                accA = __builtin_amdgcn_mfma_i32_32x32x32_i8(afr[kh*3+kw][0], b0v, accA, 0, 0, 0);
                accB = __builtin_amdgcn_mfma_i32_32x32x32_i8(afr[kh*3+kw][1], b1v, accB, 0, 0, 0);
            }
        }
        v16i acc = accA + accB;
        size_t pixbase = (size_t)rb*WWD + px;
        #pragma unroll
        for (int r = 0; r < 16; ++r) {
            int o = ot*32 + (r & 3) + 8*(r >> 2) + 4*gsel;
            cv16[(size_t)(n*C + o)*PLANE_SH + pixbase] = (short)acc[r];
        }
    }
}

// ---- K2b: per-plane exact integer stats (no atomics, no zeroing)
__global__ __launch_bounds__(256) void k_stats(
        const short* __restrict__ cv16, int* __restrict__ ps,
        long long* __restrict__ pq) {
    int plane = blockIdx.x;
    const uint2* p = (const uint2*)(cv16 + (size_t)plane*PLANE_SH);
    int s = 0; unsigned q = 0;
    for (int i = threadIdx.x; i < 3136; i += 256) {
        uint2 u = p[i];
        int v0 = (int)(short)(u.x & 0xFFFF), v1 = (int)(short)(u.x >> 16);
        int v2 = (int)(short)(u.y & 0xFFFF), v3 = (int)(short)(u.y >> 16);
        s += (v0+v1) + (v2+v3);
        q += (unsigned)(v0*v0 + v1*v1) + (unsigned)(v2*v2 + v3*v3);
    }
    __shared__ int ls[256];
    __shared__ unsigned long long lq[256];
    ls[threadIdx.x] = s; lq[threadIdx.x] = q;
    __syncthreads();
    for (int st = 128; st > 0; st >>= 1) {
        if ((int)threadIdx.x < st) {
            ls[threadIdx.x] += ls[threadIdx.x+st];
            lq[threadIdx.x] += lq[threadIdx.x+st];
        }
        __syncthreads();
    }
    if (threadIdx.x == 0) { ps[plane] = ls[0]; pq[plane] = (long long)lq[0]; }
}

// ---- K3: streaming finish (register-staged in-place), one block per plane
__global__ __launch_bounds__(256) void k_finish(
        const short* __restrict__ cv16, const float* __restrict__ x,
        const int* __restrict__ ps, const long long* __restrict__ pq,
        const float* __restrict__ wscale, const float* __restrict__ gamma,
        const float* __restrict__ beta, const float* __restrict__ b1,
        const float* __restrict__ alpha, const float* __restrict__ b2,
        float* __restrict__ out) {
    int o = blockIdx.x, n = blockIdx.y;
    size_t plane = (size_t)n*C + o;

    int s = 0; long long q = 0;
    #pragma unroll 8
    for (int nn = 0; nn < NB; ++nn) { s += ps[nn*C + o]; q += pq[nn*C + o]; }
    const float inv = 1.0f / (float)MTOT;
    float sc   = wscale[o];
    float mean = (float)s * inv;
    float ek2  = (float)q * inv;
    float mu   = sc * mean;
    float var  = sc*sc*ek2 - mu*mu;
    float g    = gamma[o] * rsqrtf(var + 1e-5f);
    float A    = g * sc;
    float B    = beta[o] - g*mu + b1[o];
    float al   = alpha[o];
    float bb2  = b2[o];

    const uint2* cv2 = (const uint2*)(cv16 + plane*PLANE_SH);
    uint2 rbuf[13];
    #pragma unroll
    for (int k = 0; k < 13; ++k) {
        int i = threadIdx.x + k*256;
        if (i < 3136) rbuf[k] = cv2[i];
    }
    __syncthreads();

    const float4* x4 = (const float4*)x + plane*3136;
    float4*       o4 = (float4*)out     + plane*3136;
    #pragma unroll
    for (int k = 0; k < 13; ++k) {
        int i = threadIdx.x + k*256;
        if (i < 3136) {
            uint2 u = rbuf[k];
            float4 xv = x4[i], r;
            float t;
            t = A * (float)(int)(short)(u.x & 0xFFFF) + B + xv.x; t = t > 0.f ? t : al*t; r.x = t + bb2;
            t = A * (float)(int)(short)(u.x >> 16)    + B + xv.y; t = t > 0.f ? t : al*t; r.y = t + bb2;
            t = A * (float)(int)(short)(u.y & 0xFFFF) + B + xv.z; t = t > 0.f ? t : al*t; r.z = t + bb2;
            t = A * (float)(int)(short)(u.y >> 16)    + B + xv.w; t = t > 0.f ? t : al*t; r.w = t + bb2;
            o4[i] = r;
        }
    }
}

extern "C" void kernel_launch(void* const* d_in, const int* in_sizes, int n_in,
                              void* d_out, int out_size, void* d_ws, size_t ws_size,
                              hipStream_t stream) {
    const float* x     = (const float*)d_in[0];
    const float* b0    = (const float*)d_in[1];
    const float* w     = (const float*)d_in[2];
    const float* gamma = (const float*)d_in[3];
    const float* beta  = (const float*)d_in[4];
    const float* b1    = (const float*)d_in[5];
    const float* alpha = (const float*)d_in[6];
    const float* b2    = (const float*)d_in[7];

    char* ws = (char*)d_ws;
    char*      A8     = ws;                                   // 36,864 B
    float*     wscale = (float*)(ws + 36864);                 // 256 B
    int*       ps     = (int*)(ws + 37120);                   // 8,192 B
    long long* pq     = (long long*)(ws + 45312);             // 16,384 B

    char*  outb = (char*)d_out;
    short* cv16 = (short*)d_out;

    hipLaunchKernelGGL(k_pack, dim3(1569), dim3(256), 0, stream,
                       x, b0, w, outb, A8, wscale);
    hipLaunchKernelGGL(k_conv, dim3(56, 32), dim3(256), 0, stream,
                       outb, A8, cv16);
    hipLaunchKernelGGL(k_stats, dim3(2048), dim3(256), 0, stream,
                       cv16, ps, pq);
    hipLaunchKernelGGL(k_finish, dim3(64, 32), dim3(256), 0, stream,
                       cv16, x, ps, pq, wscale, gamma, beta, b1, alpha, b2,
                       (float*)d_out);
}

// Round 9
// 119.702 us; speedup vs baseline: 1.0190x; 1.0071x over previous
//
#include <hip/hip_runtime.h>
#include <stdint.h>

#define C 64
#define HH 112
#define WWD 112
#define HW 12544
#define NB 32
#define MTOT (NB*HW)
#define PLANE_SH 25088      // shorts per plane stride (plane = 50176 bytes)
#define PLANE_BYTES 50176
#define ROWB 7168           // bytes per sign row (112*64)
#define HOLE_OFF 25088      // byte offset of sign-hole within a plane

typedef int v4i  __attribute__((ext_vector_type(4)));
typedef int v16i __attribute__((ext_vector_type(16)));
typedef unsigned long long ull;

// sign8 row R (R = n*112 + h) lives in the upper half of plane (R/3), 3 rows/hole
__device__ __forceinline__ const char* sign_row_c(const char* outb, int R) {
    return outb + (size_t)(R/3)*PLANE_BYTES + HOLE_OFF + (size_t)(R%3)*ROWB;
}
__device__ __forceinline__ char* sign_row(char* outb, int R) {
    return outb + (size_t)(R/3)*PLANE_BYTES + HOLE_OFF + (size_t)(R%3)*ROWB;
}

__device__ __forceinline__ uint32_t sgn_byte(float v) {
    return v > 0.f ? 1u : (v < 0.f ? 0xFFu : 0u);
}

// ---- K1: pack sign(x+b0) as NHWC int8 into d_out holes.
//  Phase 1: streaming float4 reads (16 independent 1KB wave-loads), sign-pack
//           dword -> LDS [c][pix/4] (conflict-free).
//  Phase 2: XOR-swizzled LDS gather -> NHWC 16B chunks -> coalesced 1KB stores.
__global__ __launch_bounds__(256, 4) void k_pack(
        const float* __restrict__ x, const float* __restrict__ b0,
        const float* __restrict__ w,
        char* __restrict__ outb, char* __restrict__ A8, float* __restrict__ wscale) {
    int bid = blockIdx.x;
    if (bid < 1568) {
        __shared__ uint32_t T[64*64];       // [c][pix/4] sign dwords, swizzled cols
        int tid = threadIdx.x;
        int n  = bid / 49;
        int p0 = (bid % 49) * 256;          // tile: 256 pixels of image n
        int wv = tid >> 6, L = tid & 63;
        const float* xb = x + (size_t)n*C*HW + p0 + L*4;
        #pragma unroll
        for (int i = 0; i < 16; ++i) {
            int c = wv*16 + i;
            float4 v = *(const float4*)(xb + (size_t)c*HW);
            uint32_t d = sgn_byte(v.x) | (sgn_byte(v.y) << 8)
                       | (sgn_byte(v.z) << 16) | (sgn_byte(v.w) << 24);
            T[c*64 + (L ^ (wv << 2))] = d;   // swizzle col by c>>4 (=wv)
        }
        __syncthreads();
        #pragma unroll
        for (int j = 0; j < 4; ++j) {
            int prow = wv*64 + j*16 + (L >> 2);   // pixel within tile
            int cch  = L & 3;                     // 16-channel chunk
            int col  = (prow >> 2) ^ (cch << 2);  // matches phase-1 swizzle
            int sh   = (prow & 3) * 8;
            uint32_t outw[4];
            #pragma unroll
            for (int g = 0; g < 4; ++g) {
                uint32_t acc = 0;
                #pragma unroll
                for (int b = 0; b < 4; ++b) {
                    int c = cch*16 + g*4 + b;
                    uint32_t dw = T[c*64 + col];
                    acc |= ((dw >> sh) & 0xFFu) << (8*b);
                }
                outw[g] = acc;
            }
            int gp = p0 + prow;                   // global pixel in image
            int hg = gp / WWD;
            int wg = gp - hg*WWD;
            char* dst = sign_row(outb, n*HH + hg) + wg*64 + cch*16;
            *(uint4*)dst = make_uint4(outw[0], outw[1], outw[2], outw[3]);
        }
    } else {
        int t = threadIdx.x;
        int o = t >> 2, part = t & 3;
        float s = 0.f;
        for (int cc = 0; cc < 16; ++cc) {
            int c = part*16 + cc;
            const float* wp = w + ((size_t)o*C + c)*9;
            #pragma unroll
            for (int tap = 0; tap < 9; ++tap) {
                float v = wp[tap];
                s += fabsf(v);
                A8[(o*9 + tap)*64 + c] = v > 0.f ? (char)1 : (char)-1;
            }
        }
        __shared__ float pabs[256];
        pabs[t] = s;
        __syncthreads();
        if (t < 64)
            wscale[t] = (pabs[t*4]+pabs[t*4+1]+pabs[t*4+2]+pabs[t*4+3]) * (1.0f/576.0f);
    }
}

// ---- K2: i8-MFMA conv. LDS col stride 72B (2-way banks, free), b64 reads.
__global__ __launch_bounds__(256) void k_conv(
        const char* __restrict__ signb, const char* __restrict__ A8,
        short* __restrict__ cv16) {
    __shared__ ull ldsq[4*114*9];       // 32832 B
    int n  = blockIdx.y;
    int rb = blockIdx.x * 2;            // rows rb, rb+1

    // stage rows rb-1..rb+2 (zero OOB rows)
    for (int it = threadIdx.x; it < 4*448; it += 256) {
        int ri = it / 448;
        int k  = it - ri*448;           // uint4 index in row
        int col = k >> 2;
        int b   = k & 3;
        int Rr = rb - 1 + ri;
        uint4 v = make_uint4(0,0,0,0);
        if (Rr >= 0 && Rr < HH)
            v = ((const uint4*)sign_row_c(signb, n*HH + Rr))[k];
        ull* d = &ldsq[((size_t)(ri*114 + col + 1))*9 + b*2];
        d[0] = ((ull)v.y << 32) | v.x;
        d[1] = ((ull)v.w << 32) | v.z;
    }
    // zero halo cols 0 and 113 (4 rows x 2 cols x 9 ulongs = 72)
    if (threadIdx.x < 72) {
        int r = threadIdx.x / 18, rest = threadIdx.x % 18;
        int col = (rest / 9) * 113, q = rest % 9;
        ldsq[((size_t)(r*114 + col))*9 + q] = 0ull;
    }

    int lane  = threadIdx.x & 63;
    int wv    = threadIdx.x >> 6;
    int ot    = wv & 1;                 // o-half
    int gsel  = lane >> 5;              // k-group
    int olane = ot*32 + (lane & 31);

    v4i afr[9][2];
    #pragma unroll
    for (int tap = 0; tap < 9; ++tap) {
        #pragma unroll
        for (int h = 0; h < 2; ++h)
            afr[tap][h] = *(const v4i*)(A8 + (size_t)(olane*9 + tap)*64 + h*32 + gsel*16);
    }
    __syncthreads();

    for (int T = (wv >> 1); T < 7; T += 2) {
        int px   = T*32 + (lane & 31);          // 0..223 within row-pair
        int roff = px >= WWD ? 1 : 0;
        int cpx  = px - roff*WWD;
        v16i accA = {0,0,0,0,0,0,0,0,0,0,0,0,0,0,0,0};
        v16i accB = {0,0,0,0,0,0,0,0,0,0,0,0,0,0,0,0};
        #pragma unroll
        for (int kh = 0; kh < 3; ++kh) {
            #pragma unroll
            for (int kw = 0; kw < 3; ++kw) {
                const ull* bp = &ldsq[((size_t)((roff+kh)*114 + (cpx+kw)))*9];
                ull lo0 = bp[gsel*2],     hi0 = bp[gsel*2 + 1];
                ull lo1 = bp[gsel*2 + 4], hi1 = bp[gsel*2 + 5];
                v4i b0v = {(int)lo0, (int)(lo0>>32), (int)hi0, (int)(hi0>>32)};
                v4i b1v = {(int)lo1, (int)(lo1>>32), (int)hi1, (int)(hi1>>32)};
                accA = __builtin_amdgcn_mfma_i32_32x32x32_i8(afr[kh*3+kw][0], b0v, accA, 0, 0, 0);
                accB = __builtin_amdgcn_mfma_i32_32x32x32_i8(afr[kh*3+kw][1], b1v, accB, 0, 0, 0);
            }
        }
        v16i acc = accA + accB;
        size_t pixbase = (size_t)rb*WWD + px;
        #pragma unroll
        for (int r = 0; r < 16; ++r) {
            int o = ot*32 + (r & 3) + 8*(r >> 2) + 4*gsel;
            cv16[(size_t)(n*C + o)*PLANE_SH + pixbase] = (short)acc[r];
        }
    }
}

// ---- K2b: per-plane exact integer stats (no atomics, no zeroing)
__global__ __launch_bounds__(256) void k_stats(
        const short* __restrict__ cv16, int* __restrict__ ps,
        long long* __restrict__ pq) {
    int plane = blockIdx.x;
    const uint2* p = (const uint2*)(cv16 + (size_t)plane*PLANE_SH);
    int s = 0; unsigned q = 0;
    for (int i = threadIdx.x; i < 3136; i += 256) {
        uint2 u = p[i];
        int v0 = (int)(short)(u.x & 0xFFFF), v1 = (int)(short)(u.x >> 16);
        int v2 = (int)(short)(u.y & 0xFFFF), v3 = (int)(short)(u.y >> 16);
        s += (v0+v1) + (v2+v3);
        q += (unsigned)(v0*v0 + v1*v1) + (unsigned)(v2*v2 + v3*v3);
    }
    __shared__ int ls[256];
    __shared__ unsigned long long lq[256];
    ls[threadIdx.x] = s; lq[threadIdx.x] = q;
    __syncthreads();
    for (int st = 128; st > 0; st >>= 1) {
        if ((int)threadIdx.x < st) {
            ls[threadIdx.x] += ls[threadIdx.x+st];
            lq[threadIdx.x] += lq[threadIdx.x+st];
        }
        __syncthreads();
    }
    if (threadIdx.x == 0) { ps[plane] = ls[0]; pq[plane] = (long long)lq[0]; }
}

// ---- K3: streaming finish (register-staged in-place), one block per plane
__global__ __launch_bounds__(256) void k_finish(
        const short* __restrict__ cv16, const float* __restrict__ x,
        const int* __restrict__ ps, const long long* __restrict__ pq,
        const float* __restrict__ wscale, const float* __restrict__ gamma,
        const float* __restrict__ beta, const float* __restrict__ b1,
        const float* __restrict__ alpha, const float* __restrict__ b2,
        float* __restrict__ out) {
    int o = blockIdx.x, n = blockIdx.y;
    size_t plane = (size_t)n*C + o;

    int s = 0; long long q = 0;
    #pragma unroll 8
    for (int nn = 0; nn < NB; ++nn) { s += ps[nn*C + o]; q += pq[nn*C + o]; }
    const float inv = 1.0f / (float)MTOT;
    float sc   = wscale[o];
    float mean = (float)s * inv;
    float ek2  = (float)q * inv;
    float mu   = sc * mean;
    float var  = sc*sc*ek2 - mu*mu;
    float g    = gamma[o] * rsqrtf(var + 1e-5f);
    float A    = g * sc;
    float B    = beta[o] - g*mu + b1[o];
    float al   = alpha[o];
    float bb2  = b2[o];

    const uint2* cv2 = (const uint2*)(cv16 + plane*PLANE_SH);
    uint2 rbuf[13];
    #pragma unroll
    for (int k = 0; k < 13; ++k) {
        int i = threadIdx.x + k*256;
        if (i < 3136) rbuf[k] = cv2[i];
    }
    __syncthreads();

    const float4* x4 = (const float4*)x + plane*3136;
    float4*       o4 = (float4*)out     + plane*3136;
    #pragma unroll
    for (int k = 0; k < 13; ++k) {
        int i = threadIdx.x + k*256;
        if (i < 3136) {
            uint2 u = rbuf[k];
            float4 xv = x4[i], r;
            float t;
            t = A * (float)(int)(short)(u.x & 0xFFFF) + B + xv.x; t = t > 0.f ? t : al*t; r.x = t + bb2;
            t = A * (float)(int)(short)(u.x >> 16)    + B + xv.y; t = t > 0.f ? t : al*t; r.y = t + bb2;
            t = A * (float)(int)(short)(u.y & 0xFFFF) + B + xv.z; t = t > 0.f ? t : al*t; r.z = t + bb2;
            t = A * (float)(int)(short)(u.y >> 16)    + B + xv.w; t = t > 0.f ? t : al*t; r.w = t + bb2;
            o4[i] = r;
        }
    }
}

extern "C" void kernel_launch(void* const* d_in, const int* in_sizes, int n_in,
                              void* d_out, int out_size, void* d_ws, size_t ws_size,
                              hipStream_t stream) {
    const float* x     = (const float*)d_in[0];
    const float* b0    = (const float*)d_in[1];
    const float* w     = (const float*)d_in[2];
    const float* gamma = (const float*)d_in[3];
    const float* beta  = (const float*)d_in[4];
    const float* b1    = (const float*)d_in[5];
    const float* alpha = (const float*)d_in[6];
    const float* b2    = (const float*)d_in[7];

    char* ws = (char*)d_ws;
    char*      A8     = ws;                                   // 36,864 B
    float*     wscale = (float*)(ws + 36864);                 // 256 B
    int*       ps     = (int*)(ws + 37120);                   // 8,192 B
    long long* pq     = (long long*)(ws + 45312);             // 16,384 B

    char*  outb = (char*)d_out;
    short* cv16 = (short*)d_out;

    hipLaunchKernelGGL(k_pack, dim3(1569), dim3(256), 0, stream,
                       x, b0, w, outb, A8, wscale);
    hipLaunchKernelGGL(k_conv, dim3(56, 32), dim3(256), 0, stream,
                       outb, A8, cv16);
    hipLaunchKernelGGL(k_stats, dim3(2048), dim3(256), 0, stream,
                       cv16, ps, pq);
    hipLaunchKernelGGL(k_finish, dim3(64, 32), dim3(256), 0, stream,
                       cv16, x, ps, pq, wscale, gamma, beta, b1, alpha, b2,
                       (float*)d_out);
}